// Round 5
// baseline (137.401 us; speedup 1.0000x reference)
//
#include <hip/hip_runtime.h>

// Maj3: out[n,a] = 3 * sum_{G=0..191} clip( sum_{U=0..2} p[n][U*192+G]*w[a][U*192+G], -1, 1 )
//   p flat j = c*9+u*3+v (c-major 3x3 patch, pad -1), U=j/192, G=j%192.
//
// R5: R3==R4 (23us) despite halving LDS reads -> LDS not the cap. Theory:
// weights streamed via s_load; SMEM returns out-of-order so lgkmcnt(0) full
// drains serialize every weight cluster (shared counter with ds_read).
// Fix: force weight loads onto the VMEM pipe (vmcnt: in-order, counted,
// deep) by making the channel base a VGPR via inline asm; double-buffer
// weights per channel so ch+1 loads fly under ch's 270cyc of VALU.
// Wave = 8 ch x 48 G (G-quarter), lane = position (2 w-rows x 32 h).

#define TW 2240  // 64 c * 35 h-stride words per w-plane

typedef float f4 __attribute__((ext_vector_type(4)));

__device__ __forceinline__ float clip1(float s) {
    return __builtin_amdgcn_fmed3f(s, -1.0f, 1.0f);
}

// One G-quarter: triples t = T0..T0+15 (G = 3*T0..3*T0+47) for 8 channels.
// tile word addr for (t=T0+3ci+k, U, d): Bb + ci*35 + u*TW + Kc*35 + d,
//   u = (T0+k+64U)%3, Kc = (T0+k+64U-u)/3   (compile-time per k,U)
template <int T0>
__device__ __forceinline__ void g_quarter(const float* __restrict__ tile,
                                          const float* __restrict__ wv,
                                          int Bb, float acc[8]) {
    int Bw = Bb;
#pragma unroll 1
    for (int ci = 0; ci < 5; ++ci) {
        float xv[3][3][3];
#pragma unroll
        for (int k = 0; k < 3; ++k)
#pragma unroll
            for (int U = 0; U < 3; ++U) {
                const int u   = (T0 + k + 64 * U) % 3;
                const int Kc  = (T0 + k + 64 * U - u) / 3;
                const int off = u * TW + Kc * 35;
#pragma unroll
                for (int d = 0; d < 3; ++d)
                    xv[k][U][d] = tile[Bw + off + d];
            }
        // ---- weights via VMEM (per-lane addr, runtime-uniform), dbuf ----
        float wf[2][3][9];
        {
            const float* wp = wv + 3 * T0 + 9 * ci;   // ch 0
#pragma unroll
            for (int U = 0; U < 3; ++U)
                __builtin_memcpy(&wf[0][U][0], wp + U * 192, 36);
        }
#pragma unroll
        for (int ch = 0; ch < 8; ++ch) {
            const int cur = ch & 1;
            if (ch < 7) {
                const float* wp = wv + (ch + 1) * 576 + 3 * T0 + 9 * ci;
#pragma unroll
                for (int U = 0; U < 3; ++U)
                    __builtin_memcpy(&wf[cur ^ 1][U][0], wp + U * 192, 36);
            }
            float a = acc[ch];
#pragma unroll
            for (int k = 0; k < 3; ++k)
#pragma unroll
                for (int d = 0; d < 3; ++d) {
                    float s = fmaf(xv[k][0][d], wf[cur][0][3 * k + d],
                              fmaf(xv[k][1][d], wf[cur][1][3 * k + d],
                                   xv[k][2][d] * wf[cur][2][3 * k + d]));
                    a += clip1(s);
                }
            acc[ch] = a;
        }
        Bw += 35;
    }
    // epilogue: single triple t = T0+15 (ci = 5, k = 0)
    {
        float xv[3][3];
#pragma unroll
        for (int U = 0; U < 3; ++U) {
            const int u   = (T0 + 64 * U) % 3;
            const int Kc  = (T0 + 64 * U - u) / 3;
            const int off = u * TW + Kc * 35;
#pragma unroll
            for (int d = 0; d < 3; ++d)
                xv[U][d] = tile[Bw + off + d];
        }
#pragma unroll
        for (int ch = 0; ch < 8; ++ch) {
            const float* wp = wv + ch * 576 + 3 * T0 + 45;
            float wf[3][3];
#pragma unroll
            for (int U = 0; U < 3; ++U)
#pragma unroll
                for (int q = 0; q < 3; ++q) wf[U][q] = wp[U * 192 + q];
            float a = acc[ch];
#pragma unroll
            for (int d = 0; d < 3; ++d) {
                float s = fmaf(xv[0][d], wf[0][d],
                          fmaf(xv[1][d], wf[1][d],
                               xv[2][d] * wf[2][d]));
                a += clip1(s);
            }
            acc[ch] = a;
        }
    }
}

__global__ __launch_bounds__(256, 4) void maj3_kernel(
        const float* __restrict__ x, const float* __restrict__ w,
        float* __restrict__ out) {
    __shared__ float tile[4 * TW];     // 35,840 B : [wi:4][c:64][hh:35]
    // reduction scratch reuses tile[0..1535] after all waves finish reading

    const int tid  = threadIdx.x;
    const int lane = tid & 63;
    const int wid  = tid >> 6;            // = G-quarter index
    const int blk  = blockIdx.x;          // 1024 = 128 sets * 8 ch-splits
    const int set  = blk >> 3;
    const int a0   = (blk & 7) << 3;      // block channel base (8 ch)
    const int bimg = set >> 4;
    const int w0   = (set & 15) << 1;

    // ---- stage tile[wi][c][hh] = x[bimg][w0+wi-1][hh-1][c] or -1 ----------
    // wave wid -> plane wi=wid; lane = c. Fully unrolled: 32 loads in flight.
    {
        const int wx  = w0 + wid - 1;
        const bool ok = (unsigned)wx < 32u;
        const float* xp = x + ((bimg * 32 + wx) * 32) * 64 + lane;
        float vs[34];
#pragma unroll
        for (int hh = 0; hh < 34; ++hh) {
            const int hx = hh - 1;
            vs[hh] = -1.0f;
            if (ok && (unsigned)hx < 32u) vs[hh] = xp[hx * 64];
        }
#pragma unroll
        for (int hh = 0; hh < 34; ++hh)
            tile[wid * TW + lane * 35 + hh] = vs[hh];
    }
    __syncthreads();

    // Force the weight base into a VGPR so the compiler cannot prove the
    // address wave-uniform -> emits global_load (vmcnt pipe, in-order,
    // deeply pipelined) instead of s_load (lgkmcnt(0) full drains).
    int a0v;
    asm volatile("v_mov_b32 %0, %1" : "=v"(a0v) : "s"(a0));
    const float* wv = w + a0v * 576;

    const int Bb = (lane >> 5) * TW + (lane & 31);  // wl*TW + hl

    float acc[8] = {0, 0, 0, 0, 0, 0, 0, 0};
    if      (wid == 0) g_quarter<0>(tile, wv, Bb, acc);
    else if (wid == 1) g_quarter<16>(tile, wv, Bb, acc);
    else if (wid == 2) g_quarter<32>(tile, wv, Bb, acc);
    else               g_quarter<48>(tile, wv, Bb, acc);

    __syncthreads();   // all reads of tile done -> safe to reuse as scratch
    if (wid != 0) {
#pragma unroll
        for (int k = 0; k < 8; ++k)
            tile[((wid - 1) * 8 + k) * 64 + lane] = acc[k];
    }
    __syncthreads();

    if (wid == 0) {
        const int wl = lane >> 5, hl = lane & 31;
        float* op = out + ((bimg * 32 + w0 + wl) * 32 + hl) * 64 + a0;
        f4 o0, o1;
#pragma unroll
        for (int k = 0; k < 8; ++k) {
            float v = acc[k] + tile[(0 * 8 + k) * 64 + lane]
                             + tile[(1 * 8 + k) * 64 + lane]
                             + tile[(2 * 8 + k) * 64 + lane];
            if (k < 4) o0[k] = 3.0f * v;
            else       o1[k - 4] = 3.0f * v;
        }
        *(f4*)(op)     = o0;   // a0 multiple of 8 -> 32B aligned
        *(f4*)(op + 4) = o1;
    }
}

extern "C" void kernel_launch(void* const* d_in, const int* in_sizes, int n_in,
                              void* d_out, int out_size, void* d_ws, size_t ws_size,
                              hipStream_t stream) {
    const float* x = (const float*)d_in[0];   // (8,32,32,64) f32
    const float* w = (const float*)d_in[1];   // (64,576) f32, exact +/-1.0
    float* out = (float*)d_out;               // (8,32,32,64) f32
    maj3_kernel<<<1024, 256, 0, stream>>>(x, w, out);
}

// Round 7
// 69.887 us; speedup vs baseline: 1.9660x; 1.9660x over previous
//
#include <hip/hip_runtime.h>

// Maj3 via 4-class reformulation + MFMA:
//   clip(w1x1+w2x2+w3x3) = w1 * clip(x1 + (w1w2)x2 + (w1w3)x3),  w in {+-1}
//   y[n, G*4+q] = clip(x1 +- x2 +- x3)   (q = sign pattern, fp16)
//   M[a, G*4+q] = w1 if q == pattern(a,G) else 0   (exact +-1 fp16)
//   out[n,a] = 3 * sum_k y[n,k] * M[k,a]   -> 16x16x32 f16 MFMA, K=768
// R5 post-mortem: per-channel weight streaming caused all prior stalls
// (s_load drains 23us / VMEM spills 86us). This removes it structurally.
// R6: fix cvt_pkrtz return type (__fp16 vec2, not _Float16 vec2).

typedef unsigned int u32;
typedef float f4 __attribute__((ext_vector_type(4)));
typedef _Float16 h8 __attribute__((ext_vector_type(8)));
typedef __fp16 hp2 __attribute__((ext_vector_type(2)));
typedef u32 uu2 __attribute__((ext_vector_type(2)));
typedef int i4 __attribute__((ext_vector_type(4)));

#define HS    19            // h-stride (words) in x tile: odd -> no conflicts
#define PLANE (64 * HS)     // 1216 words per w-plane
#define NP    16            // positions per block

__device__ __forceinline__ float clip1(float s) {
    return __builtin_amdgcn_fmed3f(s, -1.0f, 1.0f);
}

// ---- prep: M[a][k=G*4+q] fp16, stored as u32 pairs: M32[a*384 + G*2 + {0,1}]
__global__ __launch_bounds__(192) void prep_kernel(const float* __restrict__ w,
                                                   u32* __restrict__ M32) {
    const int a = blockIdx.x, G = threadIdx.x;
    const float w1 = w[a * 576 + G];
    const float w2 = w[a * 576 + 192 + G];
    const float w3 = w[a * 576 + 384 + G];
    const int q = ((w1 * w2 < 0.f) ? 2 : 0) + ((w1 * w3 < 0.f) ? 1 : 0);
    const u32 s1 = (w1 < 0.f) ? 0xBC00u : 0x3C00u;   // fp16 -1 : +1
    const u32 v0 = (q == 0) ? s1 : 0u, v1 = (q == 1) ? s1 : 0u;
    const u32 v2 = (q == 2) ? s1 : 0u, v3 = (q == 3) ? s1 : 0u;
    M32[a * 384 + G * 2 + 0] = v0 | (v1 << 16);
    M32[a * 384 + G * 2 + 1] = v2 | (v3 << 16);
}

// ---- phase A: 12 consecutive G starting at 9*ci0 + R0 for position-lane p.
// G = 9*ci + r: U-terms at c-offsets {0, 21+(r+3)/9, 42+(r+6)/9}, uv offsets
// {r, (r+3)%9, (r+6)%9} -- all compile-time per d. y layout: yb[(G*NP+p)*2].
template <int R0>
__device__ __forceinline__ void phaseA_12(const float* __restrict__ xt,
                                          u32* __restrict__ yb,
                                          int ci0, int p) {
#pragma unroll
    for (int d = 0; d < 12; ++d) {
        const int r    = (R0 + d) % 9;
        const int cinc = (R0 + d) / 9;              // 0 or 1
        const int uv1 = r;           const int cA = 0;
        const int uv2 = (r + 3) % 9; const int cB = 21 + (r + 3) / 9;
        const int uv3 = (r + 6) % 9; const int cC = 42 + (r + 6) / 9;
        const int ci = ci0 + cinc;
        const float x1 = xt[(uv1 / 3) * PLANE + (ci + cA) * HS + p + (uv1 % 3)];
        const float x2 = xt[(uv2 / 3) * PLANE + (ci + cB) * HS + p + (uv2 % 3)];
        const float x3 = xt[(uv3 / 3) * PLANE + (ci + cC) * HS + p + (uv3 % 3)];
        const float sp = x1 + x2, sm = x1 - x2;
        const float y0 = clip1(sp + x3), y1 = clip1(sp - x3);
        const float y2 = clip1(sm + x3), y3 = clip1(sm - x3);
        hp2 lo = __builtin_amdgcn_cvt_pkrtz(y0, y1);
        hp2 hi = __builtin_amdgcn_cvt_pkrtz(y2, y3);
        uu2 pr;
        pr.x = __builtin_bit_cast(u32, lo);
        pr.y = __builtin_bit_cast(u32, hi);
        const int G = 9 * ci + r;
        *(uu2*)&yb[(G * NP + p) * 2] = pr;          // ds_write_b64
    }
}

// ---- main: block = 16 positions (1 w-row, h-half) x all 64 channels -------
__global__ __launch_bounds__(256) void maj3_kernel(const float* __restrict__ x,
                                                   const u32* __restrict__ M32,
                                                   float* __restrict__ out) {
    __shared__ float xt[3 * PLANE];        // 14,592 B : [u:3][c:64][hh:18+pad]
    __shared__ u32  yb[192 * NP * 2];      // 24,576 B : y fp16 [G][p][q0..3]

    const int tid   = threadIdx.x;
    const int lane  = tid & 63;
    const int wid   = tid >> 6;
    const int blk   = blockIdx.x;          // 512 = bw*2 + hhalf
    const int hhalf = blk & 1;
    const int bw    = blk >> 1;            // bimg*32 + wrow
    const int bimg  = bw >> 5, wrow = bw & 31;
    const int h0    = hhalf * NP;

    // stage xt[u][c][hh] = x[bimg][wrow-1+u][h0-1+hh][c], -1 if OOB
    {
        const int c = tid & 63, slot = tid >> 6;
        const float* xb = x + (bimg * 32 * 32) * 64 + c;
#pragma unroll 1
        for (int i = slot; i < 54; i += 4) {         // 3 planes x 18 cols
            const int u = i / 18, hh = i % 18;
            const int wx = wrow - 1 + u, hx = h0 - 1 + hh;
            float v = -1.0f;
            if ((unsigned)wx < 32u && (unsigned)hx < 32u)
                v = xb[(wx * 32 + hx) * 64];
            xt[u * PLANE + c * HS + hh] = v;
        }
    }
    __syncthreads();

    // phase A: 16 (wave,sub) slots x 12 G x 16 positions
    {
        const int p = lane & 15, sub = lane >> 4;
        const int s = wid * 4 + sub;                 // 0..15
        const int ci0 = (4 * s) / 3;                 // = (12s)/9
        const int sel = s % 3;                       // r0 = 3*sel
        if (sel == 0)      phaseA_12<0>(xt, yb, ci0, p);
        else if (sel == 1) phaseA_12<3>(xt, yb, ci0, p);
        else               phaseA_12<6>(xt, yb, ci0, p);
    }
    __syncthreads();

    // phase B: wave wid -> channels a0 = wid*16; 24 K-steps of 16x16x32 f16.
    // A-frag (M): lane reads M[a0+(l&15)][k = st*32+(l>>4)*8 + 0..7] -- all 24
    // prefetched upfront (vmcnt pipe, L2-hot). B-frag (y) from LDS.
    {
        const int p16 = lane & 15, sub = lane >> 4;
        const int a0  = wid * 16;
        const u32* mp = M32 + (a0 + p16) * 384 + sub * 4;
        i4 af[24];
#pragma unroll
        for (int st = 0; st < 24; ++st)
            af[st] = *(const i4*)(mp + st * 16);

        f4 acc = {0.f, 0.f, 0.f, 0.f};
#pragma unroll
        for (int st = 0; st < 24; ++st) {
            const int Ga = st * 8 + sub * 2;
            uu2 b0 = *(const uu2*)&yb[(Ga * NP + p16) * 2];
            uu2 b1 = *(const uu2*)&yb[((Ga + 1) * NP + p16) * 2];
            i4 bi;
            bi.x = (int)b0.x; bi.y = (int)b0.y;
            bi.z = (int)b1.x; bi.w = (int)b1.y;
            acc = __builtin_amdgcn_mfma_f32_16x16x32_f16(
                      __builtin_bit_cast(h8, af[st]),
                      __builtin_bit_cast(h8, bi), acc, 0, 0, 0);
        }

        // C/D: col = lane&15 = position, row = sub*4+reg = channel (m89 map)
        const int n = bw * 32 + h0 + p16;
        float* op = out + n * 64 + a0 + sub * 4;
        f4 o;
#pragma unroll
        for (int r = 0; r < 4; ++r) o[r] = 3.0f * acc[r];
        *(f4*)op = o;
    }
}

extern "C" void kernel_launch(void* const* d_in, const int* in_sizes, int n_in,
                              void* d_out, int out_size, void* d_ws, size_t ws_size,
                              hipStream_t stream) {
    const float* x = (const float*)d_in[0];   // (8,32,32,64) f32
    const float* w = (const float*)d_in[1];   // (64,576) f32, exact +/-1.0
    float* out = (float*)d_out;               // (8,32,32,64) f32
    u32* M32 = (u32*)d_ws;                    // 98,304 B used
    prep_kernel<<<64, 192, 0, stream>>>(w, M32);
    maj3_kernel<<<512, 256, 0, stream>>>(x, M32, out);
}

// Round 8
// 66.166 us; speedup vs baseline: 2.0766x; 1.0562x over previous
//
#include <hip/hip_runtime.h>

// Maj3 via 4-class reformulation + MFMA (R7, verified correct):
//   clip(w1x1+w2x2+w3x3) = w1 * clip(x1 + (w1w2)x2 + (w1w3)x3),  w in {+-1}
//   y[n, G*4+q] = clip(x1 +- x2 +- x3)   (fp16);  M[a, G*4+q] = w1 or 0
//   out[n,a] = 3 * sum_k y[n,k] * M[k,a]   -> 16x16x32 f16 MFMA, K=768
// R8: latency-hiding pass. Staging burst-unrolled (was 14 serial vmcnt
// round-trips); af[24] M-prefetch hoisted so its L2 latency hides under
// staging drain + phase A + 2 barriers; yb relayout -> ds_read_b128 in
// phase B (24 LDS ops instead of 48). Same math, same fragment mapping.

typedef unsigned int u32;
typedef float f4 __attribute__((ext_vector_type(4)));
typedef _Float16 h8 __attribute__((ext_vector_type(8)));
typedef __fp16 hp2 __attribute__((ext_vector_type(2)));
typedef u32 uu2 __attribute__((ext_vector_type(2)));
typedef int i4 __attribute__((ext_vector_type(4)));

#define HS    19            // h-stride (words) in x tile: odd -> no conflicts
#define PLANE (64 * HS)     // 1216 words per w-plane
#define NP    16            // positions per block

__device__ __forceinline__ float clip1(float s) {
    return __builtin_amdgcn_fmed3f(s, -1.0f, 1.0f);
}

// yb index for (G, p): [(G/2)][p][ (G&1)*2 + {0,1} ]  (16B-aligned per (G/2,p))
__device__ __forceinline__ int ybi(int G, int p) {
    return ((G >> 1) * NP + p) * 4 + (G & 1) * 2;
}

// ---- prep: M[a][k=G*4+q] fp16, stored as u32 pairs: M32[a*384 + G*2 + {0,1}]
__global__ __launch_bounds__(192) void prep_kernel(const float* __restrict__ w,
                                                   u32* __restrict__ M32) {
    const int a = blockIdx.x, G = threadIdx.x;
    const float w1 = w[a * 576 + G];
    const float w2 = w[a * 576 + 192 + G];
    const float w3 = w[a * 576 + 384 + G];
    const int q = ((w1 * w2 < 0.f) ? 2 : 0) + ((w1 * w3 < 0.f) ? 1 : 0);
    const u32 s1 = (w1 < 0.f) ? 0xBC00u : 0x3C00u;   // fp16 -1 : +1
    const u32 v0 = (q == 0) ? s1 : 0u, v1 = (q == 1) ? s1 : 0u;
    const u32 v2 = (q == 2) ? s1 : 0u, v3 = (q == 3) ? s1 : 0u;
    M32[a * 384 + G * 2 + 0] = v0 | (v1 << 16);
    M32[a * 384 + G * 2 + 1] = v2 | (v3 << 16);
}

// ---- phase A: 12 consecutive G starting at 9*ci0 + R0 for position-lane p.
// G = 9*ci + r: U-terms at c-offsets {0, 21+(r+3)/9, 42+(r+6)/9}, uv offsets
// {r, (r+3)%9, (r+6)%9} -- all compile-time per d.
template <int R0>
__device__ __forceinline__ void phaseA_12(const float* __restrict__ xt,
                                          u32* __restrict__ yb,
                                          int ci0, int p) {
#pragma unroll
    for (int d = 0; d < 12; ++d) {
        const int r    = (R0 + d) % 9;
        const int cinc = (R0 + d) / 9;              // 0 or 1
        const int uv1 = r;           const int cA = 0;
        const int uv2 = (r + 3) % 9; const int cB = 21 + (r + 3) / 9;
        const int uv3 = (r + 6) % 9; const int cC = 42 + (r + 6) / 9;
        const int ci = ci0 + cinc;
        const float x1 = xt[(uv1 / 3) * PLANE + (ci + cA) * HS + p + (uv1 % 3)];
        const float x2 = xt[(uv2 / 3) * PLANE + (ci + cB) * HS + p + (uv2 % 3)];
        const float x3 = xt[(uv3 / 3) * PLANE + (ci + cC) * HS + p + (uv3 % 3)];
        const float sp = x1 + x2, sm = x1 - x2;
        const float y0 = clip1(sp + x3), y1 = clip1(sp - x3);
        const float y2 = clip1(sm + x3), y3 = clip1(sm - x3);
        hp2 lo = __builtin_amdgcn_cvt_pkrtz(y0, y1);
        hp2 hi = __builtin_amdgcn_cvt_pkrtz(y2, y3);
        uu2 pr;
        pr.x = __builtin_bit_cast(u32, lo);
        pr.y = __builtin_bit_cast(u32, hi);
        const int G = 9 * ci + r;
        *(uu2*)&yb[ybi(G, p)] = pr;                 // ds_write_b64, 8B aligned
    }
}

// ---- main: block = 16 positions (1 w-row, h-half) x all 64 channels -------
__global__ __launch_bounds__(256, 2) void maj3_kernel(
        const float* __restrict__ x, const u32* __restrict__ M32,
        float* __restrict__ out) {
    __shared__ float xt[3 * PLANE];        // 14,592 B : [u:3][c:64][hh:18+pad]
    __shared__ u32  yb[96 * NP * 4];       // 24,576 B : y fp16 [G/2][p][4]

    const int tid   = threadIdx.x;
    const int lane  = tid & 63;
    const int wid   = tid >> 6;
    const int blk   = blockIdx.x;          // 512 = bw*2 + hhalf
    const int hhalf = blk & 1;
    const int bw    = blk >> 1;            // bimg*32 + wrow
    const int bimg  = bw >> 5, wrow = bw & 31;
    const int h0    = hhalf * NP;

    const int p16 = lane & 15, sub = lane >> 4;
    const int a0  = wid * 16;

    // ---- staging loads: burst-issue 14 per thread into regs --------------
    // task i = wid + 4*j covers 0..55 (guard i<54): u = i/18, hh = i%18
    const int c = lane;
    const float* xb = x + (bimg * 32 * 32) * 64 + c;
    float vs[14];
#pragma unroll
    for (int j = 0; j < 14; ++j) {
        const int i = wid + 4 * j;
        const int u = i / 18, hh = i - u * 18;
        const int wx = wrow - 1 + u, hx = h0 - 1 + hh;
        float v = -1.0f;
        if (i < 54 && (unsigned)wx < 32u && (unsigned)hx < 32u)
            v = xb[(wx * 32 + hx) * 64];
        vs[j] = v;
    }

    // ---- hoisted M prefetch: issue now, consumed in phase B --------------
    // A-frag: lane reads M[a0+p16][u32 idx = sub*4 + st*16 + 0..3]
    const u32* mp = M32 + (a0 + p16) * 384 + sub * 4;
    i4 af[24];
#pragma unroll
    for (int st = 0; st < 24; ++st)
        af[st] = *(const i4*)(mp + st * 16);

    // ---- staging writes ---------------------------------------------------
#pragma unroll
    for (int j = 0; j < 14; ++j) {
        const int i = wid + 4 * j;
        if (i < 54) {
            const int u = i / 18, hh = i - u * 18;
            xt[u * PLANE + c * HS + hh] = vs[j];
        }
    }
    __syncthreads();

    // ---- phase A: 16 (wave,sub) slots x 12 G x 16 positions ---------------
    {
        const int s = wid * 4 + sub;                 // 0..15
        const int ci0 = (4 * s) / 3;                 // = (12s)/9
        const int sel = s % 3;                       // r0 = 3*sel
        if (sel == 0)      phaseA_12<0>(xt, yb, ci0, p16);
        else if (sel == 1) phaseA_12<3>(xt, yb, ci0, p16);
        else               phaseA_12<6>(xt, yb, ci0, p16);
    }
    __syncthreads();

    // ---- phase B: 24 K-steps of 16x16x32 f16; B-frag = one ds_read_b128 ---
    {
        f4 acc = {0.f, 0.f, 0.f, 0.f};
#pragma unroll
        for (int st = 0; st < 24; ++st) {
            // Ga = st*8 + sub*2 -> (Ga>>1) = st*4 + sub; 4 u32 contiguous
            i4 bi = *(const i4*)&yb[((st * 4 + sub) * NP + p16) * 4];
            acc = __builtin_amdgcn_mfma_f32_16x16x32_f16(
                      __builtin_bit_cast(h8, af[st]),
                      __builtin_bit_cast(h8, bi), acc, 0, 0, 0);
        }

        // C/D: col = lane&15 = position, row = sub*4+reg = channel (verified R7)
        const int n = bw * 32 + h0 + p16;
        float* op = out + n * 64 + a0 + sub * 4;
        f4 o;
#pragma unroll
        for (int r = 0; r < 4; ++r) o[r] = 3.0f * acc[r];
        *(f4*)op = o;
    }
}

extern "C" void kernel_launch(void* const* d_in, const int* in_sizes, int n_in,
                              void* d_out, int out_size, void* d_ws, size_t ws_size,
                              hipStream_t stream) {
    const float* x = (const float*)d_in[0];   // (8,32,32,64) f32
    const float* w = (const float*)d_in[1];   // (64,576) f32, exact +/-1.0
    float* out = (float*)d_out;               // (8,32,32,64) f32
    u32* M32 = (u32*)d_ws;                    // 98,304 B used
    prep_kernel<<<64, 192, 0, stream>>>(w, M32);
    maj3_kernel<<<512, 256, 0, stream>>>(x, M32, out);
}